// Round 1
// baseline (36.614 us; speedup 1.0000x reference)
//
#include <hip/hip_runtime.h>

// LIF spiking-neuron forward: x[B=64, T=100, N=4096] fp32, thresh[N] fp32.
// Sequential scan over T per (b,n) chain; B*N chains fully independent.
// mem = mem*0.5 + x_t; spk = (mem - th >= 0); mem = spk ? 0 : mem.
// TAU=0.5 => mul is exact => bitwise-identical to mul+add numpy reference.

constexpr int T = 100;
constexpr int N = 4096;
constexpr int B = 64;
constexpr float TAU = 0.5f;

__device__ __forceinline__ void lif_step(float& mem, float x, float th, float& spk) {
    float m = mem * TAU + x;       // exact mul (TAU = 0.5), one rounding on add
    float u = m - th;
    bool s = (u >= 0.0f);
    spk = s ? 1.0f : 0.0f;
    mem = s ? 0.0f : m;            // hard reset
}

__global__ __launch_bounds__(256) void lif_fwd(const float4* __restrict__ x,
                                               const float4* __restrict__ thresh4,
                                               float4* __restrict__ out) {
    const int idx = blockIdx.x * 256 + threadIdx.x;   // [0, B*N/4)
    const int n4  = idx & (N / 4 - 1);                // N/4 = 1024
    const int b   = idx >> 10;

    const float4 th = thresh4[n4];
    float4 mem = make_float4(0.f, 0.f, 0.f, 0.f);

    const long row = (long)b * T * (N / 4) + n4;
    const float4* xp = x + row;
    float4* op = out + row;

    #pragma unroll 4
    for (int t = 0; t < T; ++t) {
        const float4 xv = xp[(long)t * (N / 4)];      // coalesced 16B/lane
        float4 spk;
        lif_step(mem.x, xv.x, th.x, spk.x);
        lif_step(mem.y, xv.y, th.y, spk.y);
        lif_step(mem.z, xv.z, th.z, spk.z);
        lif_step(mem.w, xv.w, th.w, spk.w);
        op[(long)t * (N / 4)] = spk;
    }
}

extern "C" void kernel_launch(void* const* d_in, const int* in_sizes, int n_in,
                              void* d_out, int out_size, void* d_ws, size_t ws_size,
                              hipStream_t stream) {
    const float4* x  = (const float4*)d_in[0];
    const float4* th = (const float4*)d_in[1];
    float4* out = (float4*)d_out;

    const int total = B * N / 4;          // 65536 threads
    lif_fwd<<<total / 256, 256, 0, stream>>>(x, th, out);
}

// Round 2
// 35.411 us; speedup vs baseline: 1.0340x; 1.0340x over previous
//
#include <hip/hip_runtime.h>

// LIF spiking-neuron forward: x[B=64, T=100, N=4096] fp32, thresh[N] fp32.
// Sequential scan over T per (b,n) chain; B*N chains independent.
// mem = mem*0.5 + x_t; spk = (mem - th >= 0); mem = spk ? 0 : mem.
// TAU=0.5 => mul exact => bitwise-identical to numpy reference.
//
// R1: float2/thread (131072 threads -> 2 waves/SIMD) + depth-10 double-buffered
// register prefetch to fix the 1-wave/SIMD latency limit seen in R0 (36.6us,
// 5.7 TB/s effective vs 7.0 TB/s fill-kernel ceiling).

typedef float v2f __attribute__((ext_vector_type(2)));

constexpr int T = 100;
constexpr int N = 4096;
constexpr int B = 64;
constexpr int U = 10;        // prefetch group size
constexpr int NG = T / U;    // 10 groups (even, so g += 2 pairing works)
constexpr int S = N / 2;     // per-t stride in float2 units

__global__ __launch_bounds__(256) void lif_fwd(const v2f* __restrict__ x,
                                               const v2f* __restrict__ th2,
                                               v2f* __restrict__ out) {
    const int idx = blockIdx.x * 256 + threadIdx.x;   // [0, B*N/2)
    const int n2  = idx & (S - 1);                    // S = 2048
    const int b   = idx >> 11;

    const v2f th = th2[n2];
    float m0 = 0.f, m1 = 0.f;

    const long row = (long)b * T * S + n2;
    const v2f* __restrict__ xp = x + row;
    v2f* __restrict__ op = out + row;

    v2f bufA[U], bufB[U];

    // prologue: group 0 -> bufA
    #pragma unroll
    for (int u = 0; u < U; ++u) bufA[u] = xp[(long)u * S];

    for (int g = 0; g < NG; g += 2) {
        // prefetch group g+1 -> bufB (g+1 <= NG-1 always since NG even)
        #pragma unroll
        for (int u = 0; u < U; ++u) bufB[u] = xp[(long)((g + 1) * U + u) * S];

        // compute + store group g from bufA
        #pragma unroll
        for (int u = 0; u < U; ++u) {
            const v2f xv = bufA[u];
            const float a = m0 * 0.5f + xv.x;
            const float c = m1 * 0.5f + xv.y;
            const bool s0 = (a - th.x) >= 0.0f;
            const bool s1 = (c - th.y) >= 0.0f;
            v2f spk;
            spk.x = s0 ? 1.0f : 0.0f;
            spk.y = s1 ? 1.0f : 0.0f;
            m0 = s0 ? 0.0f : a;
            m1 = s1 ? 0.0f : c;
            op[(long)(g * U + u) * S] = spk;
        }

        // prefetch group g+2 -> bufA
        if (g + 2 < NG) {
            #pragma unroll
            for (int u = 0; u < U; ++u) bufA[u] = xp[(long)((g + 2) * U + u) * S];
        }

        // compute + store group g+1 from bufB
        #pragma unroll
        for (int u = 0; u < U; ++u) {
            const v2f xv = bufB[u];
            const float a = m0 * 0.5f + xv.x;
            const float c = m1 * 0.5f + xv.y;
            const bool s0 = (a - th.x) >= 0.0f;
            const bool s1 = (c - th.y) >= 0.0f;
            v2f spk;
            spk.x = s0 ? 1.0f : 0.0f;
            spk.y = s1 ? 1.0f : 0.0f;
            m0 = s0 ? 0.0f : a;
            m1 = s1 ? 0.0f : c;
            op[(long)((g + 1) * U + u) * S] = spk;
        }
    }
}

extern "C" void kernel_launch(void* const* d_in, const int* in_sizes, int n_in,
                              void* d_out, int out_size, void* d_ws, size_t ws_size,
                              hipStream_t stream) {
    const v2f* x  = (const v2f*)d_in[0];
    const v2f* th = (const v2f*)d_in[1];
    v2f* out = (v2f*)d_out;

    const int total = B * N / 2;          // 131072 threads
    lif_fwd<<<total / 256, 256, 0, stream>>>(x, th, out);
}